// Round 6
// baseline (337.056 us; speedup 1.0000x reference)
//
#include <hip/hip_runtime.h>
#include <hip/hip_bf16.h>
#include <stdint.h>

// B=4, C=96, H=W=256, heads=4, d=24, WIN=32, SUB=4
// nW=64 windows(=queries), sNW=64 sub-positions, 1024 keys/problem
// key relabel: key = pr*32 + pw*8 + ww  (attention is key-permutation invariant)
// xT fragment layout: slab(b,row,sw) = 384 uint4 units, unit = cg*32+k32,
// so an MFMA B/A fragment (16 keys x one cg) is 16 consecutive units.
#define PLANE 65536
#define SCALE_F 0.20412414523193154f  // 24^-0.5
#define PPART 1572864                 // floats per pooled partial (6 MB)
#define PSTRIDE_F2 786432             // float2 per pooled partial
#define TI_STRIDE 1572864             // bytes per 32-pixel-row key tile (32*49152)

typedef __attribute__((ext_vector_type(8))) short short8;
typedef __attribute__((ext_vector_type(4))) float f32x4;

__device__ __forceinline__ unsigned pk2(float a, float b) {
  union { __hip_bfloat162 h; unsigned u; } cv;
  cv.h = __float22bfloat162_rn(make_float2(a, b));
  return cv.u;
}

// ---------------------------------------------------------------------------
// prep: swizzle kv_w into MFMA fragment order (bf16), zero-padded d 24..31.
// (unchanged)
// ---------------------------------------------------------------------------
__global__ __launch_bounds__(256) void prep_kernel(
    const float* __restrict__ kvw, unsigned short* __restrict__ w_a1,
    unsigned short* __restrict__ w_b2) {
  int tid = blockIdx.x * 256 + threadIdx.x;  // 0..3071
  int side = tid / 1536;
  int r = tid % 1536;
  int frag = r >> 6;  // 0..23 = tile*3 + ks
  int lane = r & 63;
  int tile = frag / 3, ks = frag % 3;
  int od = tile * 16 + (lane & 15);
  int c0 = ks * 32 + (lane >> 4) * 8;
  int h = od >> 5, dd = od & 31;
  unsigned out[4] = {0u, 0u, 0u, 0u};
  if (dd < 24) {
    int row = (side == 0) ? (h * 24 + dd) : (96 + h * 24 + dd);
    const float* src = kvw + row * 96 + c0;
    float4 f0 = *(const float4*)src;
    float4 f1 = *(const float4*)(src + 4);
    out[0] = pk2(f0.x, f0.y); out[1] = pk2(f0.z, f0.w);
    out[2] = pk2(f1.x, f1.y); out[3] = pk2(f1.z, f1.w);
  }
  unsigned* dst =
      (unsigned*)((side == 0) ? w_a1 : w_b2) + (frag * 64 + lane) * 4;
  dst[0] = out[0]; dst[1] = out[1]; dst[2] = out[2]; dst[3] = out[3];
}

// ---------------------------------------------------------------------------
// tp v5: transpose x -> xT (fragment order) + coalesced partial row-pool.
// (unchanged)
// ---------------------------------------------------------------------------
__global__ __launch_bounds__(512) void tp_kernel(const float* __restrict__ x,
                                                 unsigned short* __restrict__ xT,
                                                 float2* __restrict__ part2) {
  __shared__ unsigned Lq[48 * 128];  // 24 KB: [cpair 0..47][swizzled col 0..127]
  int blk = blockIdx.x;
  int h = blk & 1;               // column half (cols [h*128, h*128+128))
  int pr = (blk >> 1) & 3;       // row within sub-row quad
  int swr = (blk >> 3) & 7;      // sub-row quad within window row
  int wh = (blk >> 6) & 7;       // window row
  int b = blk >> 9;
  int t = threadIdx.x;
  int c4l = t & 31;              // local float4-column 0..31
  int cpg = t >> 5;              // 0..15 channel-pair subgroup
  int ka = c4l >> 3;             // low 2 swizzle bits (== coll>>5)

  int r = wh * 32 + swr * 4 + pr;
  const float* xrow =
      x + ((size_t)(b * 96) * 256 + r) * 256 + (h * 32 + c4l) * 4;

  float2 pout[3];
  #pragma unroll
  for (int j = 0; j < 3; ++j) {
    int cpair = j * 16 + cpg;        // 0..47
    int cg = cpair >> 2;             // 0..11 (wave-uniform per j)
    const float* pA = xrow + (size_t)(2 * cpair) * PLANE;
    float4 vA = *(const float4*)pA;
    float4 vB = *(const float4*)(pA + PLANE);
    pout[j].x = (vA.x + vA.y) + (vA.z + vA.w);
    pout[j].y = (vB.x + vB.y) + (vB.z + vB.w);
    unsigned w0 = pk2(vA.x, vB.x), w1 = pk2(vA.y, vB.y);
    unsigned w2 = pk2(vA.z, vB.z), w3 = pk2(vA.w, vB.w);
    int K = ka | ((cg & 7) << 2);
    int base = cpair * 128;
    int c0 = 4 * c4l;
    Lq[base + ((c0 + 0) ^ K)] = w0;
    Lq[base + ((c0 + 1) ^ K)] = w1;
    Lq[base + ((c0 + 2) ^ K)] = w2;
    Lq[base + ((c0 + 3) ^ K)] = w3;
  }

  // coalesced partial-pool store: addr = base + j*512 + t
  {
    float2* pp = part2 +
        ((size_t)(((pr * 4 + b) * 8 + swr) * 8 + wh) * 2 + h) * 1536;
    #pragma unroll
    for (int j = 0; j < 3; ++j) pp[j * 512 + t] = pout[j];
  }
  __syncthreads();

  uint4* dst = (uint4*)xT + (size_t)(b * 256 + r) * 3072;
  #pragma unroll
  for (int it = 0; it < 3; ++it) {
    int id = it * 512 + t;           // 0..1535
    int sw = id / 192;               // 0..7
    int r1 = id - sw * 192;
    int cg = r1 >> 4;                // 0..11
    int r2 = r1 & 15;
    int pw = r2 >> 2, wwl = r2 & 3;
    int coll = wwl * 32 + sw * 4 + pw;       // local x-col 0..127
    int K = wwl | ((cg & 7) << 2);
    int cx = coll ^ K;
    unsigned q0 = Lq[(cg * 4 + 0) * 128 + cx];
    unsigned q1 = Lq[(cg * 4 + 1) * 128 + cx];
    unsigned q2 = Lq[(cg * 4 + 2) * 128 + cx];
    unsigned q3 = Lq[(cg * 4 + 3) * 128 + cx];
    int k32 = pw * 8 + h * 4 + wwl;          // key-within-row 0..31
    dst[sw * 384 + cg * 32 + k32] = make_uint4(q0, q1, q2, q3);
  }
}

// ---------------------------------------------------------------------------
// K1 v4: q_ws[b][s][w][co] = (pooled . q_w^T + q_b) * SCALE   (unchanged)
// ---------------------------------------------------------------------------
__global__ __launch_bounds__(256) void qgemm_kernel(
    const float2* __restrict__ part2, const float* __restrict__ qw,
    const float* __restrict__ qb, float* __restrict__ q_ws) {
  __shared__ float pl[64 * 97];
  int blk = blockIdx.x;
  int cog = blk & 3, wh = (blk >> 2) & 7, swr = (blk >> 5) & 7, b = blk >> 8;
  int t = threadIdx.x;

  const float2* base = part2 + (size_t)((b * 8 + swr) * 8 + wh) * 3072;
  #pragma unroll
  for (int k = 0; k < 12; ++k) {
    int h = k / 6;                   // 0..1
    int r2 = (k % 6) * 256 + t;      // 0..1535
    int cpair = r2 >> 5;             // 0..47
    int c4l = t & 31;
    int rest = h * 1536 + r2;
    float2 v0 = base[rest];
    float2 v1 = base[rest + PSTRIDE_F2];
    float2 v2 = base[rest + 2 * PSTRIDE_F2];
    float2 v3 = base[rest + 3 * PSTRIDE_F2];
    float sx = (v0.x + v1.x) + (v2.x + v3.x);
    float sy = (v0.y + v1.y) + (v2.y + v3.y);
    int sw = c4l & 7, ww = h * 4 + (c4l >> 3);
    int row = sw * 8 + ww;
    pl[row * 97 + 2 * cpair] = sx * 0.0625f;
    pl[row * 97 + 2 * cpair + 1] = sy * 0.0625f;
  }
  __syncthreads();

  int wv = t >> 6, lane = t & 63;
  float acc[6] = {0.f, 0.f, 0.f, 0.f, 0.f, 0.f};
  const float* qwr = qw + (cog * 24 + wv) * 96;  // co = cog*24 + k*4 + wv
  #pragma unroll 4
  for (int c = 0; c < 96; ++c) {
    float v = pl[lane * 97 + c];
    #pragma unroll
    for (int k = 0; k < 6; ++k) acc[k] += v * qwr[k * 384 + c];
  }
  int sw = lane >> 3, ww = lane & 7;
  size_t obase =
      ((size_t)((b * 64 + swr * 8 + sw) * 64) + wh * 8 + ww) * 96;
  #pragma unroll
  for (int k = 0; k < 6; ++k) {
    int co = cog * 24 + k * 4 + wv;
    q_ws[obase + co] = (acc[k] + qb[co]) * SCALE_F;
  }
}

// ---------------------------------------------------------------------------
// K2 v6: fused MFMA KV-projection + attention. block=(b,s), 512 thr, 8 waves.
// v6 vs v5:
//  (a) bxp/axp were IDENTICAL loads (rowA1==rowA2, same fo) -> single fx[2][3]
//      (halves prefetch bytes, -24 VGPR).
//  (b) prefetch issue moved AFTER B3: issue->use window (B3 .. A1') has no
//      barrier, so loads hide under PV and are never vmcnt(0)-drained by a
//      barrier (previous placement drained them at B3 after only S).
//  (c) Ps/Vs rows repacked 272->256B with XOR swizzle colb^((row&7)<<4):
//      int2 stores go 4-way -> 2-way banking (conflict-free per m136).
// LDS: Ks 26624 | Vs0 24576 | Vs1 24576 | Ps 65536 | lbuf 2048 = 143360.
// ---------------------------------------------------------------------------
__global__ __launch_bounds__(512, 2) void attn_kernel(
    const unsigned short* __restrict__ xT,
    const unsigned short* __restrict__ w_a1,
    const unsigned short* __restrict__ w_b2, const float* __restrict__ kvb,
    const float* __restrict__ q_ws, float* __restrict__ o_ws) {
  extern __shared__ __align__(16) char sm[];
  char* Ks = sm;                     // 128 rows * 208
  char* Vs0 = sm + 26624;            // 96 rows * 256 (XOR-swizzled)
  char* Vs1 = sm + 51200;            // 96 rows * 256
  char* Ps = sm + 75776;             // 4 heads * 64 rows * 256 (XOR-swizzled)
  float* lbuf = (float*)(sm + 141312);  // 2 KB

  int bs = blockIdx.x;
  int b = bs >> 6, s = bs & 63;
  int sh = s >> 3, sw = s & 7;
  int t = threadIdx.x;
  int w = t >> 6, lane = t & 63;
  int l15 = lane & 15, quad = lane >> 4;

  int mhA1 = w >> 2, nhA1 = w & 3;
  int mhA2 = w & 3, nhA2 = w >> 2;
  int head = w & 3, khalf = w >> 2;
  int nh = w >> 2;

  short8 wa[4][3], wb[4][3];
  #pragma unroll
  for (int i = 0; i < 4; ++i)
    #pragma unroll
    for (int k = 0; k < 3; ++k) {
      wa[i][k] = *(const short8*)(w_a1 + (((4 * mhA1 + i) * 3 + k) * 64 + lane) * 8);
      wb[i][k] = *(const short8*)(w_b2 + (((4 * nhA2 + i) * 3 + k) * 64 + lane) * 8);
    }

  short8 qf[4];
  #pragma unroll
  for (int nt = 0; nt < 4; ++nt) {
    short8 f = {0, 0, 0, 0, 0, 0, 0, 0};
    if (quad < 3) {
      const float* qp =
          q_ws + ((size_t)bs * 64 + nt * 16 + l15) * 96 + head * 24 + quad * 8;
      float4 a = *(const float4*)qp;
      float4 c = *(const float4*)(qp + 4);
      union { short8 s8; unsigned u[4]; } cv;
      cv.u[0] = pk2(a.x, a.y); cv.u[1] = pk2(a.z, a.w);
      cv.u[2] = pk2(c.x, c.y); cv.u[3] = pk2(c.z, c.w);
      f = cv.s8;
    }
    qf[nt] = f;
  }

  float bK[4][4];
  #pragma unroll
  for (int i = 0; i < 4; ++i) {
    int od0 = (4 * mhA1 + i) * 16 + quad * 4;
    #pragma unroll
    for (int r = 0; r < 4; ++r) {
      int od = od0 + r, dd = od & 31, h = od >> 5;
      bK[i][r] = (dd < 24) ? kvb[h * 24 + dd] : 0.f;
    }
  }
  float bV[4];
  #pragma unroll
  for (int i = 0; i < 4; ++i) {
    int vd = (4 * nhA2 + i) * 16 + l15, dd = vd & 31, h = vd >> 5;
    bV[i] = (dd < 24) ? kvb[96 + h * 24 + dd] : 0.f;
  }

  f32x4 zz = {0.f, 0.f, 0.f, 0.f};
  f32x4 oacc[2][2];
  #pragma unroll
  for (int m = 0; m < 2; ++m)
    #pragma unroll
    for (int n = 0; n < 2; ++n) oacc[m][n] = zz;
  float lacc[4] = {0.f, 0.f, 0.f, 0.f};

  const char* sb0 = (const char*)xT + (((size_t)(b * 256 + sh * 4) * 8 + sw) * 6144);

  // per-lane fragment byte offsets within a (row,sw) slab: unit = cg*32+k32
  int fo[3][2];
  #pragma unroll
  for (int k = 0; k < 3; ++k)
    #pragma unroll
    for (int hf = 0; hf < 2; ++hf)
      fo[k][hf] = (((k * 4 + quad) * 32) + hf * 16 + l15) * 16;
  int rowF = (w & 3) * 49152;  // pixel-row slab for this wave (A1 & A2 share)

  // prologue: load ti=0 fragments (shared by A1 B-operand and A2 A-operand)
  short8 fx[2][3];
  #pragma unroll
  for (int n = 0; n < 2; ++n)
    #pragma unroll
    for (int k = 0; k < 3; ++k)
      fx[n][k] = *(const short8*)(sb0 + rowF + fo[k][n]);

  for (int ti = 0; ti < 8; ++ti) {
    char* Vsb = (ti & 1) ? Vs1 : Vs0;

    // ---- A1: K-side transposed GEMM (operands already in regs) ----
    {
      f32x4 acc[4][2];
      #pragma unroll
      for (int i = 0; i < 4; ++i)
        #pragma unroll
        for (int n = 0; n < 2; ++n) {
          f32x4 a; a.x = bK[i][0]; a.y = bK[i][1]; a.z = bK[i][2]; a.w = bK[i][3];
          acc[i][n] = a;
        }
      #pragma unroll
      for (int i = 0; i < 4; ++i)
        #pragma unroll
        for (int n = 0; n < 2; ++n)
          #pragma unroll
          for (int k = 0; k < 3; ++k)
            acc[i][n] = __builtin_amdgcn_mfma_f32_16x16x32_bf16(
                wa[i][k], fx[n][k], acc[i][n], 0, 0, 0);
      #pragma unroll
      for (int i = 0; i < 4; ++i) {
        int od0 = (4 * mhA1 + i) * 16 + quad * 4;
        int dd0 = od0 & 31;
        if (dd0 < 24) {
          int h = od0 >> 5;
          #pragma unroll
          for (int n = 0; n < 2; ++n) {
            int key = (2 * nhA1 + n) * 16 + l15;
            *(int2*)(Ks + key * 208 + (h * 24 + dd0) * 2) =
                make_int2(pk2(acc[i][n].x, acc[i][n].y),
                          pk2(acc[i][n].z, acc[i][n].w));
          }
        }
      }
    }

    // ---- A2: V-side normal GEMM (256B XOR-swizzled Vs, predicated) ----
    {
      #pragma unroll
      for (int m = 0; m < 2; ++m)
        #pragma unroll
        for (int n = 0; n < 4; ++n) {
          f32x4 acc; acc.x = bV[n]; acc.y = bV[n]; acc.z = bV[n]; acc.w = bV[n];
          #pragma unroll
          for (int k = 0; k < 3; ++k)
            acc = __builtin_amdgcn_mfma_f32_16x16x32_bf16(fx[m][k], wb[n][k],
                                                          acc, 0, 0, 0);
          int vd = (4 * nhA2 + n) * 16 + l15;
          int dd = vd & 31, hh = vd >> 5;
          if (dd < 24) {
            int rowv = hh * 24 + dd;
            int colb = ((2 * mhA2 + m) * 16 + quad * 4) * 2;
            *(int2*)(Vsb + rowv * 256 + (colb ^ ((rowv & 7) << 4))) =
                make_int2(pk2(acc.x, acc.y), pk2(acc.z, acc.w));
          }
        }
    }
    __syncthreads();  // B2

    // ---- S^T = K . Q^T, exp, write P (256B XOR-swizzled) ----
    {
      f32x4 sa[4][4];
      #pragma unroll
      for (int mt = 0; mt < 4; ++mt)
        #pragma unroll
        for (int nt = 0; nt < 4; ++nt) sa[mt][nt] = zz;
      #pragma unroll
      for (int mt = 0; mt < 4; ++mt) {
        int key = khalf * 64 + mt * 16 + l15;
        short8 ak = {0, 0, 0, 0, 0, 0, 0, 0};
        if (quad < 3)
          ak = *(const short8*)(Ks + key * 208 + head * 48 + quad * 16);
        #pragma unroll
        for (int nt = 0; nt < 4; ++nt)
          sa[mt][nt] = __builtin_amdgcn_mfma_f32_16x16x32_bf16(ak, qf[nt],
                                                               sa[mt][nt], 0, 0, 0);
      }
      #pragma unroll
      for (int mt = 0; mt < 4; ++mt) {
        int colb = (khalf * 64 + mt * 16 + quad * 4) * 2;
        #pragma unroll
        for (int nt = 0; nt < 4; ++nt) {
          float e0 = __expf(sa[mt][nt].x), e1 = __expf(sa[mt][nt].y);
          float e2 = __expf(sa[mt][nt].z), e3 = __expf(sa[mt][nt].w);
          lacc[nt] += (e0 + e1) + (e2 + e3);
          int row = nt * 16 + l15;
          *(int2*)(Ps + head * 16384 + row * 256 + (colb ^ ((row & 7) << 4))) =
              make_int2(pk2(e0, e1), pk2(e2, e3));
        }
      }
      if (ti == 7) {
        #pragma unroll
        for (int nt = 0; nt < 4; ++nt) {
          float v = lacc[nt];
          v += __shfl_xor(v, 16);
          v += __shfl_xor(v, 32);
          if (quad == 0) lbuf[(head * 2 + khalf) * 64 + nt * 16 + l15] = v;
        }
      }
    }
    __syncthreads();  // B3

    // T14: issue next tile's fragment loads HERE — consumed by A1(ti+1)
    // with no intervening barrier; they hide under the whole PV phase.
    if (ti < 7) {
      const char* sbt = sb0 + (size_t)(ti + 1) * TI_STRIDE;
      #pragma unroll
      for (int n = 0; n < 2; ++n)
        #pragma unroll
        for (int k = 0; k < 3; ++k)
          fx[n][k] = *(const short8*)(sbt + rowF + fo[k][n]);
    }

    // ---- O^T += VT . P ----
    #pragma unroll
    for (int ks = 0; ks < 4; ++ks) {
      int colb = ks * 64 + quad * 16;
      short8 av[2];
      #pragma unroll
      for (int mt = 0; mt < 2; ++mt) {
        int dloc = mt * 16 + l15;
        int prow = head * 24 + (dloc < 24 ? dloc : 0);  // clamp pad rows
        av[mt] = *(const short8*)(Vsb + prow * 256 + (colb ^ ((prow & 7) << 4)));
      }
      #pragma unroll
      for (int n = 0; n < 2; ++n) {
        int row = (2 * nh + n) * 16 + l15;
        short8 bp = *(const short8*)(Ps + head * 16384 + row * 256 +
                                     (colb ^ ((row & 7) << 4)));
        #pragma unroll
        for (int mt = 0; mt < 2; ++mt)
          oacc[mt][n] = __builtin_amdgcn_mfma_f32_16x16x32_bf16(av[mt], bp,
                                                                oacc[mt][n], 0, 0, 0);
      }
    }
  }

  // ---- epilogue ----
  #pragma unroll
  for (int n = 0; n < 2; ++n) {
    int q = (2 * nh + n) * 16 + l15;
    float l = lbuf[(head * 2 + 0) * 64 + q] + lbuf[(head * 2 + 1) * 64 + q];
    float inv = 1.0f / l;
    #pragma unroll
    for (int mt = 0; mt < 2; ++mt)
      #pragma unroll
      for (int r = 0; r < 4; ++r) {
        int d = mt * 16 + quad * 4 + r;
        if (d < 24)
          o_ws[((size_t)bs * 64 + q) * 96 + head * 24 + d] = oacc[mt][n][r] * inv;
      }
  }
}

// ---------------------------------------------------------------------------
// K3 v2: proj + scatter, fused GEMM->scatter, write-coalesced. (unchanged)
// ---------------------------------------------------------------------------
__global__ __launch_bounds__(256) void proj_kernel(const float* __restrict__ o_ws,
                                                   const float* __restrict__ pw,
                                                   const float* __restrict__ pb,
                                                   float* __restrict__ out) {
  __shared__ float ol[64 * 97];
  int blk = blockIdx.x;
  int cog = blk & 3, sh = (blk >> 2) & 7, wh = (blk >> 5) & 7, b = blk >> 8;
  int t = threadIdx.x;

  // stage o tile: pair = sw*8+ww -> 96 contiguous floats each
  #pragma unroll
  for (int k = 0; k < 24; ++k) {
    int id = k * 256 + t;
    int pair = id / 96, c = id - pair * 96;
    int sw = pair >> 3, ww = pair & 7;
    ol[pair * 97 + c] =
        o_ws[(((size_t)(b * 64 + sh * 8 + sw)) * 64 + wh * 8 + ww) * 96 + c];
  }
  __syncthreads();

  int wv = t >> 6, lane = t & 63;
  int pair = (lane & 7) * 8 + (lane >> 3);  // = sw*8+ww for this lane's col
  float acc[6] = {0.f, 0.f, 0.f, 0.f, 0.f, 0.f};
  const float* pwr = pw + (cog * 24 + wv) * 96;  // co = cog*24 + k*4 + wv
  #pragma unroll 4
  for (int c = 0; c < 96; ++c) {
    float v = ol[pair * 97 + c];
    #pragma unroll
    for (int k = 0; k < 6; ++k) acc[k] += v * pwr[k * 384 + c];
  }

  // scatter: wave writes full 1KB rows; lane = col/4; 4 identical ph rows
  #pragma unroll
  for (int k = 0; k < 6; ++k) {
    int co = cog * 24 + k * 4 + wv;
    float val = acc[k] + pb[co];
    float4 pk = make_float4(val, val, val, val);
    size_t rowbase = ((size_t)(b * 96 + co) * 256 + wh * 32 + sh * 4) * 256;
    #pragma unroll
    for (int ph = 0; ph < 4; ++ph)
      *(float4*)(out + rowbase + ph * 256 + lane * 4) = pk;
  }
}

extern "C" void kernel_launch(void* const* d_in, const int* in_sizes, int n_in,
                              void* d_out, int out_size, void* d_ws,
                              size_t ws_size, hipStream_t stream) {
  const float* x = (const float*)d_in[0];
  const float* qw = (const float*)d_in[1];
  const float* qb = (const float*)d_in[2];
  const float* kvw = (const float*)d_in[3];
  const float* kvb = (const float*)d_in[4];
  const float* pw = (const float*)d_in[5];
  const float* pb = (const float*)d_in[6];

  float* pooled_part = (float*)d_ws;                          // 24 MB (4 parts)
  float* q_ws = pooled_part + 4 * PPART;                      // 6 MB
  float* o_ws = q_ws + PPART;                                 // 6 MB
  unsigned short* w_a1 = (unsigned short*)(o_ws + PPART);     // 24 KB
  unsigned short* w_b2 = w_a1 + 12288;                        // 24 KB
  unsigned short* xT = w_b2 + 12288;                          // 50.3 MB

  static int attn_lds = 143360;
  (void)hipFuncSetAttribute((const void*)attn_kernel,
                            hipFuncAttributeMaxDynamicSharedMemorySize,
                            attn_lds);

  hipLaunchKernelGGL(prep_kernel, dim3(12), dim3(256), 0, stream, kvw, w_a1, w_b2);
  hipLaunchKernelGGL(tp_kernel, dim3(2048), dim3(512), 0, stream, x, xT,
                     (float2*)pooled_part);
  hipLaunchKernelGGL(qgemm_kernel, dim3(1024), dim3(256), 0, stream,
                     (const float2*)pooled_part, qw, qb, q_ws);
  hipLaunchKernelGGL(attn_kernel, dim3(256), dim3(512), attn_lds, stream, xT,
                     w_a1, w_b2, kvb, q_ws, o_ws);
  hipLaunchKernelGGL(proj_kernel, dim3(1024), dim3(256), 0, stream, o_ws, pw, pb,
                     (float*)d_out);
}

// Round 8
// 300.016 us; speedup vs baseline: 1.1235x; 1.1235x over previous
//
#include <hip/hip_runtime.h>
#include <hip/hip_bf16.h>
#include <stdint.h>

// B=4, C=96, H=W=256, heads=4, d=24, WIN=32, SUB=4
// nW=64 windows(=queries), sNW=64 sub-positions, 1024 keys/problem
// key relabel: key = pr*32 + pw*8 + ww  (attention is key-permutation invariant)
// NOTE (R7/R8): this is the R1 configuration (best measured: 297.9us) with one
// change: attn dedupes the identical A1/A2 Xs fragment reads (12->6 ds_read_b128
// per wave per tile). The no-Xs / deep-prefetch attn variants (R5/R6) measured
// strictly worse and are abandoned. R7's bench was an infra failure; this is an
// unmodified resubmit.
#define PLANE 65536
#define SCALE_F 0.20412414523193154f  // 24^-0.5

typedef __attribute__((ext_vector_type(8))) short short8;
typedef __attribute__((ext_vector_type(4))) float f32x4;

__device__ __forceinline__ unsigned pk2(float a, float b) {
  union { __hip_bfloat162 h; unsigned u; } cv;
  cv.h = __float22bfloat162_rn(make_float2(a, b));
  return cv.u;
}

// ---------------------------------------------------------------------------
// prep: swizzle kv_w into MFMA fragment order (bf16), zero-padded d 24..31.
// ---------------------------------------------------------------------------
__global__ __launch_bounds__(256) void prep_kernel(
    const float* __restrict__ kvw, unsigned short* __restrict__ w_a1,
    unsigned short* __restrict__ w_b2) {
  int tid = blockIdx.x * 256 + threadIdx.x;  // 0..3071
  int side = tid / 1536;
  int r = tid % 1536;
  int frag = r >> 6;  // 0..23 = tile*3 + ks
  int lane = r & 63;
  int tile = frag / 3, ks = frag % 3;
  int od = tile * 16 + (lane & 15);
  int c0 = ks * 32 + (lane >> 4) * 8;
  int h = od >> 5, dd = od & 31;
  unsigned out[4] = {0u, 0u, 0u, 0u};
  if (dd < 24) {
    int row = (side == 0) ? (h * 24 + dd) : (96 + h * 24 + dd);
    const float* src = kvw + row * 96 + c0;
    float4 f0 = *(const float4*)src;
    float4 f1 = *(const float4*)(src + 4);
    out[0] = pk2(f0.x, f0.y); out[1] = pk2(f0.z, f0.w);
    out[2] = pk2(f1.x, f1.y); out[3] = pk2(f1.z, f1.w);
  }
  unsigned* dst =
      (unsigned*)((side == 0) ? w_a1 : w_b2) + (frag * 64 + lane) * 4;
  dst[0] = out[0]; dst[1] = out[1]; dst[2] = out[2]; dst[3] = out[3];
}

// ---------------------------------------------------------------------------
// tp v2 (R1): transpose x -> xT[b][row][colkey][chgrp] bf16 + fused mean-pool.
// Grid 512 = (b, wh, swr, col-half); 512 threads; 24 KB LDS.
// ---------------------------------------------------------------------------
__global__ __launch_bounds__(512) void tp_kernel(const float* __restrict__ x,
                                                 unsigned short* __restrict__ xT,
                                                 float* __restrict__ pooled) {
  __shared__ unsigned Lq[48 * 128];  // 24 KB: [cpair 0..47][swizzled col 0..127]
  int blk = blockIdx.x;
  int h = blk & 1;               // column half (cols [h*128, h*128+128))
  int swr = (blk >> 1) & 7;      // sub-row quad within window row
  int wh = (blk >> 4) & 7;       // window row
  int b = blk >> 7;
  int t = threadIdx.x;
  int c4l = t & 31;              // local float4-column 0..31
  int cpg = t >> 5;              // 0..15 channel-pair subgroup
  int ka = c4l >> 3;             // low 2 swizzle bits (== coll>>5)

  float pacc[3][2];
  #pragma unroll
  for (int j = 0; j < 3; ++j) { pacc[j][0] = 0.f; pacc[j][1] = 0.f; }

  for (int pr = 0; pr < 4; ++pr) {
    int r = wh * 32 + swr * 4 + pr;
    const float* xrow =
        x + ((size_t)(b * 96) * 256 + r) * 256 + (h * 32 + c4l) * 4;
    #pragma unroll
    for (int j = 0; j < 3; ++j) {
      int cpair = j * 16 + cpg;        // 0..47
      int cg = cpair >> 2;             // 0..11 (wave-uniform per j)
      const float* pA = xrow + (size_t)(2 * cpair) * PLANE;
      float4 vA = *(const float4*)pA;
      float4 vB = *(const float4*)(pA + PLANE);
      pacc[j][0] += (vA.x + vA.y) + (vA.z + vA.w);
      pacc[j][1] += (vB.x + vB.y) + (vB.z + vB.w);
      unsigned w0 = pk2(vA.x, vB.x), w1 = pk2(vA.y, vB.y);
      unsigned w2 = pk2(vA.z, vB.z), w3 = pk2(vA.w, vB.w);
      int K = ka | ((cg & 7) << 2);
      int base = cpair * 128;
      int c0 = 4 * c4l;
      Lq[base + ((c0 + 0) ^ K)] = w0;
      Lq[base + ((c0 + 1) ^ K)] = w1;
      Lq[base + ((c0 + 2) ^ K)] = w2;
      Lq[base + ((c0 + 3) ^ K)] = w3;
    }
    __syncthreads();
    uint4* dst = (uint4*)xT + (size_t)(b * 256 + r) * 3072;
    #pragma unroll
    for (int it = 0; it < 3; ++it) {
      int id = it * 512 + t;           // 0..1535
      int ckl = id / 12;               // 0..127
      int cg = id - ckl * 12;          // chgrp 0..11
      int sw = ckl >> 4, pw = (ckl >> 2) & 3, wwl = ckl & 3;
      int coll = wwl * 32 + sw * 4 + pw;       // local col 0..127
      int K = wwl | ((cg & 7) << 2);
      int cx = coll ^ K;
      unsigned q0 = Lq[(cg * 4 + 0) * 128 + cx];
      unsigned q1 = Lq[(cg * 4 + 1) * 128 + cx];
      unsigned q2 = Lq[(cg * 4 + 2) * 128 + cx];
      unsigned q3 = Lq[(cg * 4 + 3) * 128 + cx];
      int colkey = sw * 32 + pw * 8 + h * 4 + wwl;
      dst[colkey * 12 + cg] = make_uint4(q0, q1, q2, q3);
    }
    __syncthreads();
  }
  int sw = c4l & 7, ww = h * 4 + (c4l >> 3);
  #pragma unroll
  for (int j = 0; j < 3; ++j)
    #pragma unroll
    for (int e = 0; e < 2; ++e) {
      int ch = 2 * (j * 16 + cpg) + e;
      pooled[(((size_t)(b * 64 + swr * 8 + sw)) * 96 + ch) * 64 + wh * 8 + ww] =
          pacc[j][e] * 0.0625f;
    }
}

// ---------------------------------------------------------------------------
// K1 v2 (R1): q_ws[b][s][w][co] = (pooled . q_w^T + q_b) * SCALE   (fp32)
// Grid 1024 = (bs, co-group of 24). c-outer loop: 96 LDS reads/thread.
// ---------------------------------------------------------------------------
__global__ __launch_bounds__(256) void qgemm_kernel(
    const float* __restrict__ pooled, const float* __restrict__ qw,
    const float* __restrict__ qb, float* __restrict__ q_ws) {
  __shared__ float pl[64 * 97];
  int blk = blockIdx.x;
  int cog = blk & 3, bs = blk >> 2;
  int t = threadIdx.x;
  const float* src = pooled + (size_t)bs * 6144;
  #pragma unroll
  for (int k = 0; k < 24; ++k) {
    int idx = t + k * 256;  // [c][w]
    int c = idx >> 6, w = idx & 63;
    pl[w * 97 + c] = src[idx];
  }
  __syncthreads();
  int wv = t >> 6, lane = t & 63;
  float acc[6] = {0.f, 0.f, 0.f, 0.f, 0.f, 0.f};
  const float* qwr = qw + (cog * 24 + wv) * 96;  // co = cog*24 + k*4 + wv
  #pragma unroll 4
  for (int c = 0; c < 96; ++c) {
    float v = pl[lane * 97 + c];
    #pragma unroll
    for (int k = 0; k < 6; ++k) acc[k] += v * qwr[k * 384 + c];
  }
  #pragma unroll
  for (int k = 0; k < 6; ++k) {
    int co = cog * 24 + k * 4 + wv;
    q_ws[((size_t)bs * 64 + lane) * 96 + co] = (acc[k] + qb[co]) * SCALE_F;
  }
}

// ---------------------------------------------------------------------------
// K2 (R1 + dedupe): fused MFMA KV-projection + attention. block=(b,s),
// 512 thr, 8 waves. Xs-staged (loads at loop top — best measured config).
// R7 change: A1's bx and A2's ax read IDENTICAL Xs addresses (nhA1==mhA2=w&3,
// same quad/swizzle) -> single fx[2][3] load shared by both GEMMs.
// ---------------------------------------------------------------------------
__global__ __launch_bounds__(512, 2) void attn_kernel(
    const unsigned short* __restrict__ xT,
    const unsigned short* __restrict__ w_a1,
    const unsigned short* __restrict__ w_b2, const float* __restrict__ kvb,
    const float* __restrict__ q_ws, float* __restrict__ o_ws) {
  extern __shared__ __align__(16) char sm[];
  char* Xs = sm;                 // 32768
  char* Ks = sm + 32768;         // 26624 (rows 208)
  char* Vs = sm + 59392;         // 34816 (rows 272)
  char* Ps = sm + 94208;         // 69632 (per-head 17408, rows 272)
  float* lbuf = (float*)sm;      // aliases Xs

  int bs = blockIdx.x;
  int b = bs >> 6, s = bs & 63;
  int sh = s >> 3, sw = s & 7;
  int t = threadIdx.x;
  int w = t >> 6, lane = t & 63;
  int l15 = lane & 15, quad = lane >> 4;

  int mhA1 = w >> 2;
  int nhA2 = w >> 2;
  int head = w & 3, khalf = w >> 2;
  int nh = w >> 2;
  int kt = w & 3;  // shared A1-n / A2-m key-tile pair index (nhA1 == mhA2)

  short8 wa[4][3], wb[4][3];
  #pragma unroll
  for (int i = 0; i < 4; ++i)
    #pragma unroll
    for (int k = 0; k < 3; ++k) {
      wa[i][k] = *(const short8*)(w_a1 + (((4 * mhA1 + i) * 3 + k) * 64 + lane) * 8);
      wb[i][k] = *(const short8*)(w_b2 + (((4 * nhA2 + i) * 3 + k) * 64 + lane) * 8);
    }

  short8 qf[4];
  #pragma unroll
  for (int nt = 0; nt < 4; ++nt) {
    short8 f = {0, 0, 0, 0, 0, 0, 0, 0};
    if (quad < 3) {
      const float* qp =
          q_ws + ((size_t)bs * 64 + nt * 16 + l15) * 96 + head * 24 + quad * 8;
      float4 a = *(const float4*)qp;
      float4 c = *(const float4*)(qp + 4);
      union { short8 s8; unsigned u[4]; } cv;
      cv.u[0] = pk2(a.x, a.y); cv.u[1] = pk2(a.z, a.w);
      cv.u[2] = pk2(c.x, c.y); cv.u[3] = pk2(c.z, c.w);
      f = cv.s8;
    }
    qf[nt] = f;
  }

  float bK[4][4];
  #pragma unroll
  for (int i = 0; i < 4; ++i) {
    int od0 = (4 * mhA1 + i) * 16 + quad * 4;
    #pragma unroll
    for (int r = 0; r < 4; ++r) {
      int od = od0 + r, dd = od & 31, h = od >> 5;
      bK[i][r] = (dd < 24) ? kvb[h * 24 + dd] : 0.f;
    }
  }
  float bV[4];
  #pragma unroll
  for (int i = 0; i < 4; ++i) {
    int vd = (4 * nhA2 + i) * 16 + l15, dd = vd & 31, h = vd >> 5;
    bV[i] = (dd < 24) ? kvb[96 + h * 24 + dd] : 0.f;
  }

  f32x4 zz = {0.f, 0.f, 0.f, 0.f};
  f32x4 oacc[2][2];
  #pragma unroll
  for (int m = 0; m < 2; ++m)
    #pragma unroll
    for (int n = 0; n < 2; ++n) oacc[m][n] = zz;
  float lacc[4] = {0.f, 0.f, 0.f, 0.f};

  const char* sb0 = (const char*)xT + (((size_t)(b * 256 + sh * 4) * 8 + sw) * 6144);

  for (int ti = 0; ti < 8; ++ti) {
    const char* sb = sb0 + (size_t)ti * 32 * 8 * 6144;
    #pragma unroll
    for (int i = 0; i < 3; ++i) {
      int l = i * 512 + t;
      int pr = l / 384;  // wave-uniform
      int rem = l - pr * 384;
      int key = pr * 32 + rem / 12;
      int c = rem - (rem / 12) * 12;
      uint4 v = *(const uint4*)(sb + (size_t)pr * 49152 + (size_t)rem * 16);
      *(uint4*)(Xs + key * 256 + ((c ^ (key & 7)) << 4)) = v;
    }
    __syncthreads();  // B1

    // shared Xs fragments for A1 (B-operand) and A2 (A-operand)
    short8 fx[2][3];
    #pragma unroll
    for (int n = 0; n < 2; ++n) {
      int key = (2 * kt + n) * 16 + l15;
      #pragma unroll
      for (int k = 0; k < 3; ++k)
        fx[n][k] = *(const short8*)(Xs + key * 256 +
                                    (((k * 4 + quad) ^ (key & 7)) << 4));
    }

    // ---- A1: K-side transposed GEMM ----
    {
      f32x4 acc[4][2];
      #pragma unroll
      for (int i = 0; i < 4; ++i)
        #pragma unroll
        for (int n = 0; n < 2; ++n) {
          f32x4 a; a.x = bK[i][0]; a.y = bK[i][1]; a.z = bK[i][2]; a.w = bK[i][3];
          acc[i][n] = a;
        }
      #pragma unroll
      for (int i = 0; i < 4; ++i)
        #pragma unroll
        for (int n = 0; n < 2; ++n)
          #pragma unroll
          for (int k = 0; k < 3; ++k)
            acc[i][n] = __builtin_amdgcn_mfma_f32_16x16x32_bf16(
                wa[i][k], fx[n][k], acc[i][n], 0, 0, 0);
      #pragma unroll
      for (int i = 0; i < 4; ++i) {
        int od0 = (4 * mhA1 + i) * 16 + quad * 4;
        int dd0 = od0 & 31;
        if (dd0 < 24) {
          int h = od0 >> 5;
          #pragma unroll
          for (int n = 0; n < 2; ++n) {
            int key = (2 * kt + n) * 16 + l15;
            *(int2*)(Ks + key * 208 + (h * 24 + dd0) * 2) =
                make_int2(pk2(acc[i][n].x, acc[i][n].y),
                          pk2(acc[i][n].z, acc[i][n].w));
          }
        }
      }
    }

    // ---- A2: V-side normal GEMM (A-operand = same fx fragments) ----
    {
      #pragma unroll
      for (int m = 0; m < 2; ++m)
        #pragma unroll
        for (int n = 0; n < 4; ++n) {
          f32x4 acc; acc.x = bV[n]; acc.y = bV[n]; acc.z = bV[n]; acc.w = bV[n];
          #pragma unroll
          for (int k = 0; k < 3; ++k)
            acc = __builtin_amdgcn_mfma_f32_16x16x32_bf16(fx[m][k], wb[n][k],
                                                          acc, 0, 0, 0);
          int vd = (4 * nhA2 + n) * 16 + l15;
          int key0 = (2 * kt + m) * 16 + quad * 4;
          *(int2*)(Vs + vd * 272 + key0 * 2) =
              make_int2(pk2(acc.x, acc.y), pk2(acc.z, acc.w));
        }
    }
    __syncthreads();  // B2

    // ---- S^T = K . Q^T, exp, write P ----
    {
      f32x4 sa[4][4];
      #pragma unroll
      for (int mt = 0; mt < 4; ++mt)
        #pragma unroll
        for (int nt = 0; nt < 4; ++nt) sa[mt][nt] = zz;
      #pragma unroll
      for (int mt = 0; mt < 4; ++mt) {
        int key = khalf * 64 + mt * 16 + l15;
        short8 ak = {0, 0, 0, 0, 0, 0, 0, 0};
        if (quad < 3)
          ak = *(const short8*)(Ks + key * 208 + head * 48 + quad * 16);
        #pragma unroll
        for (int nt = 0; nt < 4; ++nt)
          sa[mt][nt] = __builtin_amdgcn_mfma_f32_16x16x32_bf16(ak, qf[nt],
                                                               sa[mt][nt], 0, 0, 0);
      }
      #pragma unroll
      for (int mt = 0; mt < 4; ++mt) {
        int key0 = khalf * 64 + mt * 16 + quad * 4;
        #pragma unroll
        for (int nt = 0; nt < 4; ++nt) {
          float e0 = __expf(sa[mt][nt].x), e1 = __expf(sa[mt][nt].y);
          float e2 = __expf(sa[mt][nt].z), e3 = __expf(sa[mt][nt].w);
          lacc[nt] += (e0 + e1) + (e2 + e3);
          *(int2*)(Ps + head * 17408 + (nt * 16 + l15) * 272 + key0 * 2) =
              make_int2(pk2(e0, e1), pk2(e2, e3));
        }
      }
      if (ti == 7) {
        #pragma unroll
        for (int nt = 0; nt < 4; ++nt) {
          float v = lacc[nt];
          v += __shfl_xor(v, 16);
          v += __shfl_xor(v, 32);
          if (quad == 0) lbuf[(head * 2 + khalf) * 64 + nt * 16 + l15] = v;
        }
      }
    }
    __syncthreads();  // B3

    // ---- O^T += VT . P ----
    #pragma unroll
    for (int ks = 0; ks < 4; ++ks) {
      short8 av[2];
      #pragma unroll
      for (int mt = 0; mt < 2; ++mt)
        av[mt] = *(const short8*)(Vs + (head * 32 + mt * 16 + l15) * 272 +
                                  ks * 64 + quad * 16);
      #pragma unroll
      for (int n = 0; n < 2; ++n) {
        short8 bp = *(const short8*)(Ps + head * 17408 +
                                     ((2 * nh + n) * 16 + l15) * 272 +
                                     ks * 64 + quad * 16);
        #pragma unroll
        for (int mt = 0; mt < 2; ++mt)
          oacc[mt][n] = __builtin_amdgcn_mfma_f32_16x16x32_bf16(av[mt], bp,
                                                                oacc[mt][n], 0, 0, 0);
      }
    }
  }

  // ---- epilogue ----
  #pragma unroll
  for (int n = 0; n < 2; ++n) {
    int q = (2 * nh + n) * 16 + l15;
    float l = lbuf[(head * 2 + 0) * 64 + q] + lbuf[(head * 2 + 1) * 64 + q];
    float inv = 1.0f / l;
    #pragma unroll
    for (int mt = 0; mt < 2; ++mt)
      #pragma unroll
      for (int r = 0; r < 4; ++r) {
        int d = mt * 16 + quad * 4 + r;
        if (d < 24)
          o_ws[((size_t)bs * 64 + q) * 96 + head * 24 + d] = oacc[mt][n][r] * inv;
      }
  }
}

// ---------------------------------------------------------------------------
// K3 v2 (R1): proj + scatter, fused GEMM->scatter, write-coalesced.
// Grid 1024 = (b, wh, sh, co-group of 24).
// ---------------------------------------------------------------------------
__global__ __launch_bounds__(256) void proj_kernel(const float* __restrict__ o_ws,
                                                   const float* __restrict__ pw,
                                                   const float* __restrict__ pb,
                                                   float* __restrict__ out) {
  __shared__ float ol[64 * 97];
  int blk = blockIdx.x;
  int cog = blk & 3, sh = (blk >> 2) & 7, wh = (blk >> 5) & 7, b = blk >> 8;
  int t = threadIdx.x;

  // stage o tile: pair = sw*8+ww -> 96 contiguous floats each
  #pragma unroll
  for (int k = 0; k < 24; ++k) {
    int id = k * 256 + t;
    int pair = id / 96, c = id - pair * 96;
    int sw = pair >> 3, ww = pair & 7;
    ol[pair * 97 + c] =
        o_ws[(((size_t)(b * 64 + sh * 8 + sw)) * 64 + wh * 8 + ww) * 96 + c];
  }
  __syncthreads();

  int wv = t >> 6, lane = t & 63;
  int pair = (lane & 7) * 8 + (lane >> 3);  // = sw*8+ww for this lane's col
  float acc[6] = {0.f, 0.f, 0.f, 0.f, 0.f, 0.f};
  const float* pwr = pw + (cog * 24 + wv) * 96;  // co = cog*24 + k*4 + wv
  #pragma unroll 4
  for (int c = 0; c < 96; ++c) {
    float v = ol[pair * 97 + c];
    #pragma unroll
    for (int k = 0; k < 6; ++k) acc[k] += v * pwr[k * 384 + c];
  }

  // scatter: wave writes full 1KB rows; lane = col/4; 4 identical ph rows
  #pragma unroll
  for (int k = 0; k < 6; ++k) {
    int co = cog * 24 + k * 4 + wv;
    float val = acc[k] + pb[co];
    float4 pk = make_float4(val, val, val, val);
    size_t rowbase = ((size_t)(b * 96 + co) * 256 + wh * 32 + sh * 4) * 256;
    #pragma unroll
    for (int ph = 0; ph < 4; ++ph)
      *(float4*)(out + rowbase + ph * 256 + lane * 4) = pk;
  }
}

extern "C" void kernel_launch(void* const* d_in, const int* in_sizes, int n_in,
                              void* d_out, int out_size, void* d_ws,
                              size_t ws_size, hipStream_t stream) {
  const float* x = (const float*)d_in[0];
  const float* qw = (const float*)d_in[1];
  const float* qb = (const float*)d_in[2];
  const float* kvw = (const float*)d_in[3];
  const float* kvb = (const float*)d_in[4];
  const float* pw = (const float*)d_in[5];
  const float* pb = (const float*)d_in[6];

  float* pooled = (float*)d_ws;                              // 6 MB
  float* q_ws = pooled + 1572864;                            // 6 MB
  float* o_ws = q_ws + 1572864;                              // 6 MB
  unsigned short* w_a1 = (unsigned short*)(o_ws + 1572864);  // 24 KB
  unsigned short* w_b2 = w_a1 + 12288;                       // 24 KB
  unsigned short* xT = w_b2 + 12288;                         // 50.3 MB

  static int attn_lds = 163840;
  (void)hipFuncSetAttribute((const void*)attn_kernel,
                            hipFuncAttributeMaxDynamicSharedMemorySize,
                            attn_lds);

  hipLaunchKernelGGL(prep_kernel, dim3(12), dim3(256), 0, stream, kvw, w_a1, w_b2);
  hipLaunchKernelGGL(tp_kernel, dim3(512), dim3(512), 0, stream, x, xT, pooled);
  hipLaunchKernelGGL(qgemm_kernel, dim3(1024), dim3(256), 0, stream, pooled, qw,
                     qb, q_ws);
  hipLaunchKernelGGL(attn_kernel, dim3(256), dim3(512), attn_lds, stream, xT,
                     w_a1, w_b2, kvb, q_ws, o_ws);
  hipLaunchKernelGGL(proj_kernel, dim3(1024), dim3(256), 0, stream, o_ws, pw, pb,
                     (float*)d_out);
}